// Round 2
// baseline (438.754 us; speedup 1.0000x reference)
//
#include <hip/hip_runtime.h>
#include <hip/hip_bf16.h>
#include <stdint.h>

// StaticGraphLSTMCell: B=512, N=21, I=256, H=1024, NT=5
// out = [hy (B*N*H) | cy (B*N*H) | gx_out (N*N)] fp32
//
// ws layout (bytes):
//   Wc   bf16 [5][4096][1280]   @ 0          (52,428,800)
//   Xc   bf16 [21][512][1280]   @ 52,428,800 (27,525,120)
//   gates bf16 [512][21][4096]  @ 79,953,920 (88,080,384)
//   gx   f32  [21][21]          @ 168,034,304 (1,764)

typedef __bf16 bf16_t;
typedef __bf16 bf16x8 __attribute__((ext_vector_type(8)));
typedef float f32x4 __attribute__((ext_vector_type(4)));
typedef float f32x16 __attribute__((ext_vector_type(16)));

#define NB 512
#define NN 21
#define NI 256
#define NH 1024
#define KDIM 1280
#define ODIM 4096
#define BNH (512ull * 21 * 1024)

__device__ inline void gld16(const void* g, const void* l) {
  __builtin_amdgcn_global_load_lds(
      (const __attribute__((address_space(1))) unsigned int*)g,
      (__attribute__((address_space(3))) unsigned int*)l, 16, 0, 0);
}

__device__ inline float sigmoid_fast(float x) {
  return 1.0f / (1.0f + __expf(-x));
}
__device__ inline float tanh_fast(float x) {
  float ax = fabsf(x);
  float e = __expf(2.0f * ax);  // inf-safe: 2/(inf+1)=0 -> 1
  float t = 1.0f - 2.0f / (e + 1.0f);
  return copysignf(t, x);
}

// raw workgroup barrier: no vmcnt drain; memory clobber keeps LDS ops ordered
__device__ inline void wg_barrier() {
  asm volatile("" ::: "memory");
  __builtin_amdgcn_s_barrier();
  asm volatile("" ::: "memory");
}

// ---- merged prep: pack weights, pack activations, gx normalize -------------
// blocks [0, 12800): pack_w ; [12800, 19520): pack_x ; 19520: gx
__global__ __launch_bounds__(256) void pack_all(
    const float* __restrict__ wih, const float* __restrict__ whh,
    const float* __restrict__ input, const float* __restrict__ hx,
    const float* __restrict__ G, bf16_t* __restrict__ Wc,
    bf16_t* __restrict__ Xc, float* __restrict__ gxw,
    float* __restrict__ gxout) {
  const int bx = blockIdx.x;
  const int tid = threadIdx.x;
  if (bx < 12800) {
    int c = bx * 256 + tid;  // chunk of 8; total 3,276,800
    int k8 = c % (KDIM / 8);
    int row = c / (KDIM / 8);
    int k = k8 * 8;
    const float* src = (k < NI) ? (wih + (size_t)row * NI + k)
                                : (whh + (size_t)row * NH + (k - NI));
    float4 a = *(const float4*)src;
    float4 b = *(const float4*)(src + 4);
    bf16x8 o;
    o[0] = (bf16_t)a.x; o[1] = (bf16_t)a.y; o[2] = (bf16_t)a.z; o[3] = (bf16_t)a.w;
    o[4] = (bf16_t)b.x; o[5] = (bf16_t)b.y; o[6] = (bf16_t)b.z; o[7] = (bf16_t)b.w;
    *(bf16x8*)&Wc[(size_t)c * 8] = o;
  } else if (bx < 19520) {
    int c = (bx - 12800) * 256 + tid;  // total 1,720,320
    int k8 = c % (KDIM / 8);
    int rest = c / (KDIM / 8);  // n*512 + b
    int n = rest / NB;
    int b = rest % NB;
    int k = k8 * 8;
    const float* src = (k < NI) ? (input + ((size_t)b * NN + n) * NI + k)
                                : (hx + ((size_t)b * NN + n) * NH + (k - NI));
    float4 a = *(const float4*)src;
    float4 d = *(const float4*)(src + 4);
    bf16x8 o;
    o[0] = (bf16_t)a.x; o[1] = (bf16_t)a.y; o[2] = (bf16_t)a.z; o[3] = (bf16_t)a.w;
    o[4] = (bf16_t)d.x; o[5] = (bf16_t)d.y; o[6] = (bf16_t)d.z; o[7] = (bf16_t)d.w;
    *(bf16x8*)&Xc[(size_t)c * 8] = o;
  } else {
    int m = tid;
    if (m < NN) {
      float s = 0.f;
      for (int j = 0; j < NN; j++) s += fabsf(G[m * NN + j]);
      s = fmaxf(s, 1e-12f);
      float row[NN];
      float s2 = 0.f;
      for (int j = 0; j < NN; j++) {
        row[j] = G[m * NN + j] / s;
        s2 += fabsf(row[j]);
      }
      s2 = fmaxf(s2, 1e-12f);
      for (int j = 0; j < NN; j++) {
        gxw[m * NN + j] = row[j];
        gxout[m * NN + j] = row[j] / s2;
      }
    }
  }
}

// ---- GEMM: 256x256 tile, BK=32, 8 waves (2M x 4N), 4-slot LDS pipeline -----
// per node n (blockIdx.z): gates[b][n][o] = Xc[n][b][:] . Wc[tau][o][:] + bias
//
// 32x32x16 MFMA: per K-tile per wave = 12 ds_read_b128 + 16 MFMA (vs 16+32
// for 16x16x32) -> 25% less LDS traffic, higher pipe rate.
// Swizzle: 16B chunk, phys = lc ^ swz(R), swz(R) = ((R>>1)^(R>>3))&3
//   -> 32-row b128 fragment reads are bank-balanced (8 words/bank = floor).
//   Applied to global source at stage time (gld_lds writes linearly) and to
//   the ds_read address (both-sides-or-neither).
// Schedule per tile t: {12 ds_read (slot t&3) | 4 gld -> slot (t+2)&3 |
//   16 MFMA (compiler-counted lgkm) | vmcnt(4) | s_barrier}.
// ONE barrier + ONE vmcnt per K-tile; never vmcnt(0) in steady state.
// Hazards: end-of-t vmcnt(4)+barrier publishes tile t+1 (issued at t-1);
// gld(t+2) overwrites slot read at t-2, protected by end-of-(t-1) barrier.
__global__ __launch_bounds__(512, 2) void gemm_bt(
    const bf16_t* __restrict__ Xc, const bf16_t* __restrict__ Wc,
    const float* __restrict__ bhh, const int* __restrict__ node_types,
    bf16_t* __restrict__ gates) {
  __shared__ char lds[4 * 32768];

  const int n = blockIdx.z;
  const int tau = node_types[n];
  const bf16_t* A = Xc + (size_t)n * NB * KDIM;
  const bf16_t* Bw = Wc + (size_t)tau * ODIM * KDIM;

  const int tid = threadIdx.x;
  const int lane = tid & 63;
  const int w = tid >> 6;          // 0..7
  const int wm = (w & 1) * 128;    // wave M offset
  const int wn = (w >> 1) * 64;    // wave N offset
  const int lr = lane & 31;        // row within a 32-tile
  const int hi = lane >> 5;        // k-half (0: k0..7, 1: k8..15)

  const int m0 = blockIdx.y * 256;
  const int n0 = blockIdx.x * 256;

  // fragment read byte offsets (kstep s=0; s=1 is ^32)
  int aoffs[4], boffs[2];
#pragma unroll
  for (int i = 0; i < 4; i++) {
    int R = wm + i * 32 + lr;
    int phys = (hi ^ ((R >> 1) ^ (R >> 3))) & 3;
    aoffs[i] = R * 64 + phys * 16;
  }
#pragma unroll
  for (int j = 0; j < 2; j++) {
    int R = wn + j * 32 + lr;
    int phys = (hi ^ ((R >> 1) ^ (R >> 3))) & 3;
    boffs[j] = 16384 + R * 64 + phys * 16;
  }

  // staging: wave-contiguous 16B chunks (lane l writes base + l*16 -> linear)
  const int ca = w * 128 + lane;
  const int cb = ca + 64;
  const int rA0 = ca >> 2, cA0 = (ca & 3) ^ (((rA0 >> 1) ^ (rA0 >> 3)) & 3);
  const int rA1 = cb >> 2, cA1 = (cb & 3) ^ (((rA1 >> 1) ^ (rA1 >> 3)) & 3);
  const bf16_t* gA0 = A + (size_t)(m0 + rA0) * KDIM + cA0 * 8;
  const bf16_t* gA1 = A + (size_t)(m0 + rA1) * KDIM + cA1 * 8;
  const bf16_t* gB0 = Bw + (size_t)(n0 + rA0) * KDIM + cA0 * 8;
  const bf16_t* gB1 = Bw + (size_t)(n0 + rA1) * KDIM + cA1 * 8;
  const int dA0 = ca * 16, dA1 = cb * 16;

  f32x16 acc[4][2];
#pragma unroll
  for (int i = 0; i < 4; i++)
#pragma unroll
    for (int j = 0; j < 2; j++)
#pragma unroll
      for (int e = 0; e < 16; e++) acc[i][j][e] = 0.f;

  // prologue: stage K-tiles 0 (slot0) and 1 (slot1)
  {
    char* L0 = lds;
    char* L1 = lds + 32768;
    gld16(gA0, L0 + dA0);          gld16(gA1, L0 + dA1);
    gld16(gB0, L0 + 16384 + dA0);  gld16(gB1, L0 + 16384 + dA1);
    gld16(gA0 + 32, L1 + dA0);         gld16(gA1 + 32, L1 + dA1);
    gld16(gB0 + 32, L1 + 16384 + dA0); gld16(gB1 + 32, L1 + 16384 + dA1);
    asm volatile("s_waitcnt vmcnt(4)" ::: "memory");  // tile 0 landed
    wg_barrier();
  }

  for (int t = 0; t < 40; ++t) {
    const char* P = lds + (t & 3) * 32768;
    bf16x8 af[4][2], bfr[2][2];
#pragma unroll
    for (int j = 0; j < 2; j++) {
      bfr[j][0] = *(const bf16x8*)(P + boffs[j]);
      bfr[j][1] = *(const bf16x8*)(P + (boffs[j] ^ 32));
    }
#pragma unroll
    for (int i = 0; i < 4; i++) {
      af[i][0] = *(const bf16x8*)(P + aoffs[i]);
      af[i][1] = *(const bf16x8*)(P + (aoffs[i] ^ 32));
    }
    if (t < 38) {
      char* Wd = lds + ((t + 2) & 3) * 32768;
      const int kk = (t + 2) * 32;
      gld16(gA0 + kk, Wd + dA0);          gld16(gA1 + kk, Wd + dA1);
      gld16(gB0 + kk, Wd + 16384 + dA0);  gld16(gB1 + kk, Wd + 16384 + dA1);
    }
    __builtin_amdgcn_s_setprio(1);
#pragma unroll
    for (int i = 0; i < 4; i++)
#pragma unroll
      for (int j = 0; j < 2; j++) {
        acc[i][j] = __builtin_amdgcn_mfma_f32_32x32x16_bf16(af[i][0], bfr[j][0], acc[i][j], 0, 0, 0);
        acc[i][j] = __builtin_amdgcn_mfma_f32_32x32x16_bf16(af[i][1], bfr[j][1], acc[i][j], 0, 0, 0);
      }
    __builtin_amdgcn_s_setprio(0);
    if (t < 38)       asm volatile("s_waitcnt vmcnt(4)" ::: "memory");
    else if (t == 38) asm volatile("s_waitcnt vmcnt(0)" ::: "memory");
    if (t < 39) wg_barrier();
  }

  float bv[2];
#pragma unroll
  for (int j = 0; j < 2; j++) bv[j] = bhh[tau * ODIM + n0 + wn + j * 32 + lr];
#pragma unroll
  for (int i = 0; i < 4; i++) {
#pragma unroll
    for (int j = 0; j < 2; j++) {
      const int o = n0 + wn + j * 32 + lr;
#pragma unroll
      for (int q = 0; q < 4; q++) {
#pragma unroll
        for (int rr = 0; rr < 4; rr++) {
          int b = m0 + wm + i * 32 + rr + 8 * q + 4 * hi;
          gates[((size_t)b * NN + n) * ODIM + o] =
              (bf16_t)(acc[i][j][q * 4 + rr] + bv[j]);
        }
      }
    }
  }
}

// ---- fused mix + pointwise LSTM --------------------------------------------
template <int M0C, int CH>
__device__ inline void mix_chunk(const bf16_t (*gs)[4][256],
                                 const float* __restrict__ gx,
                                 const float* __restrict__ cx,
                                 float* __restrict__ out, int b, int h, int tid,
                                 bool cmask) {
  float a[CH][4];
#pragma unroll
  for (int mm = 0; mm < CH; mm++) {
    a[mm][0] = 0.f; a[mm][1] = 0.f; a[mm][2] = 0.f; a[mm][3] = 0.f;
  }
  for (int nn = 0; nn < NN; nn++) {
    float v0 = (float)gs[nn][0][tid];
    float v1 = (float)gs[nn][1][tid];
    float v2 = (float)gs[nn][2][tid];
    float v3 = (float)gs[nn][3][tid];
#pragma unroll
    for (int mm = 0; mm < CH; mm++) {
      float wgt = gx[(M0C + mm) * NN + nn];  // wave-uniform -> SGPR
      a[mm][0] = fmaf(wgt, v0, a[mm][0]);
      a[mm][1] = fmaf(wgt, v1, a[mm][1]);
      a[mm][2] = fmaf(wgt, v2, a[mm][2]);
      a[mm][3] = fmaf(wgt, v3, a[mm][3]);
    }
  }
#pragma unroll
  for (int mm = 0; mm < CH; mm++) {
    int m = M0C + mm;
    size_t off = ((size_t)b * NN + m) * NH + h;
    float c0 = cx[off];
    float ig = sigmoid_fast(a[mm][0]);
    float fg = sigmoid_fast(a[mm][1]);
    float cg = tanh_fast(a[mm][2]);
    float og = sigmoid_fast(a[mm][3]);
    float c = cmask ? fmaf(fg, c0, ig * cg) : c0;
    out[off] = og * tanh_fast(c);
    out[BNH + off] = c;
  }
}

__global__ __launch_bounds__(256) void mix_lstm(const bf16_t* __restrict__ gates,
                                                const float* __restrict__ gx,
                                                const float* __restrict__ cx,
                                                const int* __restrict__ t_ptr,
                                                float* __restrict__ out) {
  __shared__ bf16_t gs[NN][4][256];  // 43,008 B
  const int tid = threadIdx.x;
  const int b = blockIdx.y;
  const int h0 = blockIdx.x * 256;
  const size_t gb = (size_t)b * NN * ODIM;
  for (int i = tid; i < NN * 4 * 32; i += 256) {
    int nn = i >> 7;
    int rem = i & 127;
    int g = rem >> 5;
    int c = rem & 31;
    *(bf16x8*)&gs[nn][g][c * 8] =
        *(const bf16x8*)&gates[gb + (size_t)nn * ODIM + g * NH + h0 + c * 8];
  }
  __syncthreads();

  const int h = h0 + tid;
  const float tf = (float)(t_ptr[0] + 1);
  float phase = floorf((float)h / 1023.0f * 8.0f + 1.0f);  // 1..9
  bool cmask = fmodf(tf, phase) < 0.01f;

  mix_chunk<0, 11>(gs, gx, cx, out, b, h, tid, cmask);
  mix_chunk<11, 10>(gs, gx, cx, out, b, h, tid, cmask);
}

extern "C" void kernel_launch(void* const* d_in, const int* in_sizes, int n_in,
                              void* d_out, int out_size, void* d_ws, size_t ws_size,
                              hipStream_t stream) {
  const float* input = (const float*)d_in[0];
  const float* hx = (const float*)d_in[1];
  const float* cx = (const float*)d_in[2];
  const float* G = (const float*)d_in[3];
  const float* wih = (const float*)d_in[4];
  const float* whh = (const float*)d_in[5];
  const float* bhh = (const float*)d_in[6];
  const int* node_types = (const int*)d_in[7];
  const int* t = (const int*)d_in[8];
  float* out = (float*)d_out;

  char* ws = (char*)d_ws;
  bf16_t* Wc = (bf16_t*)ws;
  bf16_t* Xc = (bf16_t*)(ws + 52428800);
  bf16_t* gates = (bf16_t*)(ws + 79953920);
  float* gxw = (float*)(ws + 168034304);

  pack_all<<<19521, 256, 0, stream>>>(wih, whh, input, hx, G, Wc, Xc, gxw,
                                      out + 2 * BNH);
  dim3 gg(ODIM / 256, NB / 256, NN);  // (16, 2, 21)
  gemm_bt<<<gg, 512, 0, stream>>>(Xc, Wc, bhh, node_types, gates);
  dim3 gm(NH / 256, NB);  // (4, 512)
  mix_lstm<<<gm, 256, 0, stream>>>(gates, gxw, cx, t, out);
}

// Round 3
// 417.271 us; speedup vs baseline: 1.0515x; 1.0515x over previous
//
#include <hip/hip_runtime.h>
#include <hip/hip_bf16.h>
#include <stdint.h>

// StaticGraphLSTMCell: B=512, N=21, I=256, H=1024, NT=5
// out = [hy (B*N*H) | cy (B*N*H) | gx_out (N*N)] fp32
//
// ws layout (bytes):
//   Wc   bf16 [5][4096][1280]   @ 0          (52,428,800)
//   Xc   bf16 [21][512][1280]   @ 52,428,800 (27,525,120)
//   gates bf16 [512][21][4096]  @ 79,953,920 (88,080,384)
//   gx   f32  [21][21]          @ 168,034,304 (1,764)

typedef __bf16 bf16_t;
typedef __bf16 bf16x8 __attribute__((ext_vector_type(8)));
typedef float f32x4 __attribute__((ext_vector_type(4)));

#define NB 512
#define NN 21
#define NI 256
#define NH 1024
#define KDIM 1280
#define ODIM 4096
#define BNH (512ull * 21 * 1024)

__device__ inline void gld16(const void* g, const void* l) {
  __builtin_amdgcn_global_load_lds(
      (const __attribute__((address_space(1))) unsigned int*)g,
      (__attribute__((address_space(3))) unsigned int*)l, 16, 0, 0);
}

__device__ inline float sigmoid_fast(float x) {
  return 1.0f / (1.0f + __expf(-x));
}
__device__ inline float tanh_fast(float x) {
  float ax = fabsf(x);
  float e = __expf(2.0f * ax);  // inf-safe: 2/(inf+1)=0 -> 1
  float t = 1.0f - 2.0f / (e + 1.0f);
  return copysignf(t, x);
}

__device__ inline void wg_barrier() {
  asm volatile("" ::: "memory");
  __builtin_amdgcn_s_barrier();
  asm volatile("" ::: "memory");
}

// ---- merged prep: pack weights, pack activations, gx normalize -------------
__global__ __launch_bounds__(256) void pack_all(
    const float* __restrict__ wih, const float* __restrict__ whh,
    const float* __restrict__ input, const float* __restrict__ hx,
    const float* __restrict__ G, bf16_t* __restrict__ Wc,
    bf16_t* __restrict__ Xc, float* __restrict__ gxw,
    float* __restrict__ gxout) {
  const int bx = blockIdx.x;
  const int tid = threadIdx.x;
  if (bx < 12800) {
    int c = bx * 256 + tid;
    int k8 = c % (KDIM / 8);
    int row = c / (KDIM / 8);
    int k = k8 * 8;
    const float* src = (k < NI) ? (wih + (size_t)row * NI + k)
                                : (whh + (size_t)row * NH + (k - NI));
    float4 a = *(const float4*)src;
    float4 b = *(const float4*)(src + 4);
    bf16x8 o;
    o[0] = (bf16_t)a.x; o[1] = (bf16_t)a.y; o[2] = (bf16_t)a.z; o[3] = (bf16_t)a.w;
    o[4] = (bf16_t)b.x; o[5] = (bf16_t)b.y; o[6] = (bf16_t)b.z; o[7] = (bf16_t)b.w;
    *(bf16x8*)&Wc[(size_t)c * 8] = o;
  } else if (bx < 19520) {
    int c = (bx - 12800) * 256 + tid;
    int k8 = c % (KDIM / 8);
    int rest = c / (KDIM / 8);  // n*512 + b
    int n = rest / NB;
    int b = rest % NB;
    int k = k8 * 8;
    const float* src = (k < NI) ? (input + ((size_t)b * NN + n) * NI + k)
                                : (hx + ((size_t)b * NN + n) * NH + (k - NI));
    float4 a = *(const float4*)src;
    float4 d = *(const float4*)(src + 4);
    bf16x8 o;
    o[0] = (bf16_t)a.x; o[1] = (bf16_t)a.y; o[2] = (bf16_t)a.z; o[3] = (bf16_t)a.w;
    o[4] = (bf16_t)d.x; o[5] = (bf16_t)d.y; o[6] = (bf16_t)d.z; o[7] = (bf16_t)d.w;
    *(bf16x8*)&Xc[(size_t)c * 8] = o;
  } else {
    int m = tid;
    if (m < NN) {
      float s = 0.f;
      for (int j = 0; j < NN; j++) s += fabsf(G[m * NN + j]);
      s = fmaxf(s, 1e-12f);
      float row[NN];
      float s2 = 0.f;
      for (int j = 0; j < NN; j++) {
        row[j] = G[m * NN + j] / s;
        s2 += fabsf(row[j]);
      }
      s2 = fmaxf(s2, 1e-12f);
      for (int j = 0; j < NN; j++) {
        gxw[m * NN + j] = row[j];
        gxout[m * NN + j] = row[j] / s2;
      }
    }
  }
}

// ---- GEMM: 128x256 block, BK=64, 4 waves, single-buffer 48 KiB LDS ---------
// gates[b][n][o] = Xc[n][b][:] . Wc[tau][o][:] + bias   (per node n)
//
// 2 blocks/CU resident (48 KiB LDS, <=256 VGPR): two unsynced blocks
// interleave so one block's MFMA covers the other's read/stage phases.
//
// LDS: A[128 rows][64k] bf16 @0 (16 KiB); B @16384 (32 KiB), B rows permuted:
//   lds row' = q_n*128 + w*32 + rr  <->  logical B row R = w*64 + q_n*32 + rr
//   so each staging half (B0 = rows' 0-127, B1 = 128-255) is contiguous.
// Swizzle (G4-validated for 128-B rows): 16B chunk, phys = lc ^ (row & 7),
//   applied to the global source at stage time (gld_lds writes linearly)
//   and to the ds_read address.
// Per K-tile (BK=64): 4 phases, each {ds_reads | stage half | barrier |
//   lgkmcnt(0)+sched_barrier | setprio(1) 16 MFMA setprio(0) | counted vmcnt |
//   barrier}. Wave tile 128x64: quadrants (q_m,q_n) of 64x32, K=64 each.
//   P0: read A-lo(8)+B0(4), mfma (0,0);             wait vmcnt(2)  [B1 landed]
//   P1: read B1(4), stage A-lo'+B0'(6), mfma (0,1); wait vmcnt(6)  [A-hi landed]
//   P2: read A-hi(8), stage B1'(4), mfma (1,1)
//   P3: stage A-hi'(2), mfma (1,0) [b0 held in regs]; wait vmcnt(6) [A-lo',B0']
// vmcnt FIFO (steady): enter P0 with [B1(4),Ahi(2)]; P1 +[Alo'2,B0'4];
// P2 +[B1'4]; P3 +[Ahi'2] -> 12, drain to 6. Never 0 in steady state.
// WAR: each region is overwritten only in the phase after its last read,
// separated by the end-of-phase barrier.
__global__ __launch_bounds__(256, 2) void gemm_bt(
    const bf16_t* __restrict__ Xc, const bf16_t* __restrict__ Wc,
    const float* __restrict__ bhh, const int* __restrict__ node_types,
    bf16_t* __restrict__ gates) {
  __shared__ char lds[49152];

  // XCD-bijective remap: 1344 = 8*168; XCD k gets logical blocks [168k,168k+168)
  const int bid = blockIdx.x;
  const int l = (bid & 7) * 168 + (bid >> 3);
  const int n = l / 64;
  const int rem = l & 63;
  const int m0 = (rem >> 4) * 128;
  const int n0 = (rem & 15) * 256;

  const int tau = node_types[n];
  const bf16_t* An = Xc + (size_t)n * NB * KDIM;
  const bf16_t* Bt = Wc + (size_t)tau * ODIM * KDIM;

  const int tid = threadIdx.x;
  const int lane = tid & 63;
  const int w = tid >> 6;      // 0..3
  const int r = lane & 15;
  const int quad = lane >> 4;

  // fragment read offsets: phys16B = (kk*4+quad) ^ (r&7); kk=1 is ^64 bytes
  const int pA = (quad ^ (r & 7)) * 16;
  const int aoff = r * 128 + pA;                      // + i*2048 + q_m*8192
  const int boff = 16384 + w * 4096 + r * 128 + pA;   // + j*2048 + q_n*16384

  // staging pointers (A-hi = A-lo + 64*KDIM, B1 = B0 + 32*KDIM; same lc)
  const bf16_t* sAlo[2];
  const bf16_t* sB0[4];
#pragma unroll
  for (int p = 0; p < 2; p++) {
    int ci = tid + p * 256;
    int row = ci >> 3, lc = (ci & 7) ^ (row & 7);
    sAlo[p] = An + (size_t)(m0 + row) * KDIM + lc * 8;
  }
#pragma unroll
  for (int p = 0; p < 4; p++) {
    int ci = tid + p * 256;
    int lr = ci >> 3, lc = (ci & 7) ^ (lr & 7);
    int R0 = (lr >> 5) * 64 + (lr & 31);
    sB0[p] = Bt + (size_t)(n0 + R0) * KDIM + lc * 8;
  }

  f32x4 acc[8][4];
#pragma unroll
  for (int i = 0; i < 8; i++)
#pragma unroll
    for (int j = 0; j < 4; j++) acc[i][j] = {0.f, 0.f, 0.f, 0.f};

  // prologue: stage tile 0, FIFO order [Alo, B0, B1, Ahi]; keep [B1,Ahi] flying
  {
#pragma unroll
    for (int p = 0; p < 2; p++) gld16(sAlo[p], lds + tid * 16 + p * 4096);
#pragma unroll
    for (int p = 0; p < 4; p++) gld16(sB0[p], lds + 16384 + tid * 16 + p * 4096);
#pragma unroll
    for (int p = 0; p < 4; p++)
      gld16(sB0[p] + 32 * KDIM, lds + 32768 + tid * 16 + p * 4096);
#pragma unroll
    for (int p = 0; p < 2; p++)
      gld16(sAlo[p] + 64 * KDIM, lds + 8192 + tid * 16 + p * 4096);
#pragma unroll
    for (int p = 0; p < 2; p++) sAlo[p] += 64;
#pragma unroll
    for (int p = 0; p < 4; p++) sB0[p] += 64;
    asm volatile("s_waitcnt vmcnt(6)" ::: "memory");
    wg_barrier();
  }

  bf16x8 af[4][2], b0v[2][2], b1v[2][2];

  for (int t = 0; t < 20; ++t) {
    const bool st = (t < 19);
    // ---------------- P0: A-lo + B0 reads, mfma quad (0,0)
#pragma unroll
    for (int i = 0; i < 4; i++) {
      af[i][0] = *(const bf16x8*)(lds + (aoff + i * 2048));
      af[i][1] = *(const bf16x8*)(lds + ((aoff + i * 2048) ^ 64));
    }
#pragma unroll
    for (int j = 0; j < 2; j++) {
      b0v[j][0] = *(const bf16x8*)(lds + (boff + j * 2048));
      b0v[j][1] = *(const bf16x8*)(lds + ((boff + j * 2048) ^ 64));
    }
    wg_barrier();
    asm volatile("s_waitcnt lgkmcnt(0)" ::: "memory");
    __builtin_amdgcn_sched_barrier(0);
    __builtin_amdgcn_s_setprio(1);
#pragma unroll
    for (int i = 0; i < 4; i++)
#pragma unroll
      for (int j = 0; j < 2; j++) {
        acc[i][j] = __builtin_amdgcn_mfma_f32_16x16x32_bf16(af[i][0], b0v[j][0], acc[i][j], 0, 0, 0);
        acc[i][j] = __builtin_amdgcn_mfma_f32_16x16x32_bf16(af[i][1], b0v[j][1], acc[i][j], 0, 0, 0);
      }
    __builtin_amdgcn_s_setprio(0);
    asm volatile("s_waitcnt vmcnt(2)" ::: "memory");  // B1(t) landed
    wg_barrier();

    // ---------------- P1: B1 reads, stage A-lo'+B0', mfma quad (0,1)
#pragma unroll
    for (int j = 0; j < 2; j++) {
      b1v[j][0] = *(const bf16x8*)(lds + (boff + 16384 + j * 2048));
      b1v[j][1] = *(const bf16x8*)(lds + ((boff + 16384 + j * 2048) ^ 64));
    }
    if (st) {
#pragma unroll
      for (int p = 0; p < 2; p++) gld16(sAlo[p], lds + tid * 16 + p * 4096);
#pragma unroll
      for (int p = 0; p < 4; p++) gld16(sB0[p], lds + 16384 + tid * 16 + p * 4096);
    }
    wg_barrier();
    asm volatile("s_waitcnt lgkmcnt(0)" ::: "memory");
    __builtin_amdgcn_sched_barrier(0);
    __builtin_amdgcn_s_setprio(1);
#pragma unroll
    for (int i = 0; i < 4; i++)
#pragma unroll
      for (int j = 0; j < 2; j++) {
        acc[i][2 + j] = __builtin_amdgcn_mfma_f32_16x16x32_bf16(af[i][0], b1v[j][0], acc[i][2 + j], 0, 0, 0);
        acc[i][2 + j] = __builtin_amdgcn_mfma_f32_16x16x32_bf16(af[i][1], b1v[j][1], acc[i][2 + j], 0, 0, 0);
      }
    __builtin_amdgcn_s_setprio(0);
    if (st) asm volatile("s_waitcnt vmcnt(6)" ::: "memory");   // A-hi(t) landed
    else    asm volatile("s_waitcnt vmcnt(0)" ::: "memory");
    wg_barrier();

    // ---------------- P2: A-hi reads, stage B1', mfma quad (1,1)
#pragma unroll
    for (int i = 0; i < 4; i++) {
      af[i][0] = *(const bf16x8*)(lds + (aoff + 8192 + i * 2048));
      af[i][1] = *(const bf16x8*)(lds + ((aoff + 8192 + i * 2048) ^ 64));
    }
    if (st) {
#pragma unroll
      for (int p = 0; p < 4; p++)
        gld16(sB0[p] + 32 * KDIM, lds + 32768 + tid * 16 + p * 4096);
    }
    wg_barrier();
    asm volatile("s_waitcnt lgkmcnt(0)" ::: "memory");
    __builtin_amdgcn_sched_barrier(0);
    __builtin_amdgcn_s_setprio(1);
#pragma unroll
    for (int i = 0; i < 4; i++)
#pragma unroll
      for (int j = 0; j < 2; j++) {
        acc[4 + i][2 + j] = __builtin_amdgcn_mfma_f32_16x16x32_bf16(af[i][0], b1v[j][0], acc[4 + i][2 + j], 0, 0, 0);
        acc[4 + i][2 + j] = __builtin_amdgcn_mfma_f32_16x16x32_bf16(af[i][1], b1v[j][1], acc[4 + i][2 + j], 0, 0, 0);
      }
    __builtin_amdgcn_s_setprio(0);
    wg_barrier();

    // ---------------- P3: stage A-hi', mfma quad (1,0) with held b0v
    if (st) {
#pragma unroll
      for (int p = 0; p < 2; p++)
        gld16(sAlo[p] + 64 * KDIM, lds + 8192 + tid * 16 + p * 4096);
    }
    wg_barrier();
    __builtin_amdgcn_s_setprio(1);
#pragma unroll
    for (int i = 0; i < 4; i++)
#pragma unroll
      for (int j = 0; j < 2; j++) {
        acc[4 + i][j] = __builtin_amdgcn_mfma_f32_16x16x32_bf16(af[i][0], b0v[j][0], acc[4 + i][j], 0, 0, 0);
        acc[4 + i][j] = __builtin_amdgcn_mfma_f32_16x16x32_bf16(af[i][1], b0v[j][1], acc[4 + i][j], 0, 0, 0);
      }
    __builtin_amdgcn_s_setprio(0);
    if (st) asm volatile("s_waitcnt vmcnt(6)" ::: "memory");  // A-lo',B0' landed
    wg_barrier();

#pragma unroll
    for (int p = 0; p < 2; p++) sAlo[p] += 64;
#pragma unroll
    for (int p = 0; p < 4; p++) sB0[p] += 64;
  }

  float bv[4];
#pragma unroll
  for (int j = 0; j < 4; j++) bv[j] = bhh[tau * ODIM + n0 + w * 64 + j * 16 + r];
#pragma unroll
  for (int i = 0; i < 8; i++) {
    int brow = m0 + i * 16 + quad * 4;
#pragma unroll
    for (int j = 0; j < 4; j++) {
      int o = n0 + w * 64 + j * 16 + r;
#pragma unroll
      for (int reg = 0; reg < 4; reg++) {
        int b = brow + reg;
        gates[((size_t)b * NN + n) * ODIM + o] = (bf16_t)(acc[i][j][reg] + bv[j]);
      }
    }
  }
}

// ---- fused mix + pointwise LSTM --------------------------------------------
template <int M0C, int CH>
__device__ inline void mix_chunk(const bf16_t (*gs)[4][256],
                                 const float* __restrict__ gx,
                                 const float* __restrict__ cx,
                                 float* __restrict__ out, int b, int h, int tid,
                                 bool cmask) {
  float a[CH][4];
#pragma unroll
  for (int mm = 0; mm < CH; mm++) {
    a[mm][0] = 0.f; a[mm][1] = 0.f; a[mm][2] = 0.f; a[mm][3] = 0.f;
  }
  for (int nn = 0; nn < NN; nn++) {
    float v0 = (float)gs[nn][0][tid];
    float v1 = (float)gs[nn][1][tid];
    float v2 = (float)gs[nn][2][tid];
    float v3 = (float)gs[nn][3][tid];
#pragma unroll
    for (int mm = 0; mm < CH; mm++) {
      float wgt = gx[(M0C + mm) * NN + nn];  // wave-uniform -> SGPR
      a[mm][0] = fmaf(wgt, v0, a[mm][0]);
      a[mm][1] = fmaf(wgt, v1, a[mm][1]);
      a[mm][2] = fmaf(wgt, v2, a[mm][2]);
      a[mm][3] = fmaf(wgt, v3, a[mm][3]);
    }
  }
#pragma unroll
  for (int mm = 0; mm < CH; mm++) {
    int m = M0C + mm;
    size_t off = ((size_t)b * NN + m) * NH + h;
    float c0 = cx[off];
    float ig = sigmoid_fast(a[mm][0]);
    float fg = sigmoid_fast(a[mm][1]);
    float cg = tanh_fast(a[mm][2]);
    float og = sigmoid_fast(a[mm][3]);
    float c = cmask ? fmaf(fg, c0, ig * cg) : c0;
    out[off] = og * tanh_fast(c);
    out[BNH + off] = c;
  }
}

__global__ __launch_bounds__(256) void mix_lstm(const bf16_t* __restrict__ gates,
                                                const float* __restrict__ gx,
                                                const float* __restrict__ cx,
                                                const int* __restrict__ t_ptr,
                                                float* __restrict__ out) {
  __shared__ bf16_t gs[NN][4][256];  // 43,008 B
  const int tid = threadIdx.x;
  const int b = blockIdx.y;
  const int h0 = blockIdx.x * 256;
  const size_t gb = (size_t)b * NN * ODIM;
  for (int i = tid; i < NN * 4 * 32; i += 256) {
    int nn = i >> 7;
    int rem = i & 127;
    int g = rem >> 5;
    int c = rem & 31;
    *(bf16x8*)&gs[nn][g][c * 8] =
        *(const bf16x8*)&gates[gb + (size_t)nn * ODIM + g * NH + h0 + c * 8];
  }
  __syncthreads();

  const int h = h0 + tid;
  const float tf = (float)(t_ptr[0] + 1);
  float phase = floorf((float)h / 1023.0f * 8.0f + 1.0f);  // 1..9
  bool cmask = fmodf(tf, phase) < 0.01f;

  mix_chunk<0, 11>(gs, gx, cx, out, b, h, tid, cmask);
  mix_chunk<11, 10>(gs, gx, cx, out, b, h, tid, cmask);
}

extern "C" void kernel_launch(void* const* d_in, const int* in_sizes, int n_in,
                              void* d_out, int out_size, void* d_ws, size_t ws_size,
                              hipStream_t stream) {
  const float* input = (const float*)d_in[0];
  const float* hx = (const float*)d_in[1];
  const float* cx = (const float*)d_in[2];
  const float* G = (const float*)d_in[3];
  const float* wih = (const float*)d_in[4];
  const float* whh = (const float*)d_in[5];
  const float* bhh = (const float*)d_in[6];
  const int* node_types = (const int*)d_in[7];
  const int* t = (const int*)d_in[8];
  float* out = (float*)d_out;

  char* ws = (char*)d_ws;
  bf16_t* Wc = (bf16_t*)ws;
  bf16_t* Xc = (bf16_t*)(ws + 52428800);
  bf16_t* gates = (bf16_t*)(ws + 79953920);
  float* gxw = (float*)(ws + 168034304);

  pack_all<<<19521, 256, 0, stream>>>(wih, whh, input, hx, G, Wc, Xc, gxw,
                                      out + 2 * BNH);
  gemm_bt<<<1344, 256, 0, stream>>>(Xc, Wc, bhh, node_types, gates);
  dim3 gm(NH / 256, NB);  // (4, 512)
  mix_lstm<<<gm, 256, 0, stream>>>(gates, gxw, cx, t, out);
}

// Round 4
// 404.967 us; speedup vs baseline: 1.0834x; 1.0304x over previous
//
#include <hip/hip_runtime.h>
#include <hip/hip_bf16.h>
#include <stdint.h>

// StaticGraphLSTMCell: B=512, N=21, I=256, H=1024, NT=5
// out = [hy (B*N*H) | cy (B*N*H) | gx_out (N*N)] fp32
//
// ws layout (bytes):
//   Wc   bf16 [5][4096][1280]   @ 0          (52,428,800)
//   Xc   bf16 [21][512][1280]   @ 52,428,800 (27,525,120)
//   gates bf16 [512][21][4096]  @ 79,953,920 (88,080,384)
//   gx   f32  [21][21]          @ 168,034,304 (1,764)

typedef __bf16 bf16_t;
typedef __bf16 bf16x8 __attribute__((ext_vector_type(8)));
typedef float f32x4 __attribute__((ext_vector_type(4)));

#define NB 512
#define NN 21
#define NI 256
#define NH 1024
#define KDIM 1280
#define ODIM 4096
#define BNH (512ull * 21 * 1024)

__device__ inline void gld16(const void* g, const void* l) {
  __builtin_amdgcn_global_load_lds(
      (const __attribute__((address_space(1))) unsigned int*)g,
      (__attribute__((address_space(3))) unsigned int*)l, 16, 0, 0);
}

__device__ inline float sigmoid_fast(float x) {
  return 1.0f / (1.0f + __expf(-x));
}
__device__ inline float tanh_fast(float x) {
  float ax = fabsf(x);
  float e = __expf(2.0f * ax);  // inf-safe: 2/(inf+1)=0 -> 1
  float t = 1.0f - 2.0f / (e + 1.0f);
  return copysignf(t, x);
}

__device__ inline void wg_barrier() {
  asm volatile("" ::: "memory");
  __builtin_amdgcn_s_barrier();
  asm volatile("" ::: "memory");
}

// ---- merged prep: pack weights, pack activations, gx normalize -------------
__global__ __launch_bounds__(256) void pack_all(
    const float* __restrict__ wih, const float* __restrict__ whh,
    const float* __restrict__ input, const float* __restrict__ hx,
    const float* __restrict__ G, bf16_t* __restrict__ Wc,
    bf16_t* __restrict__ Xc, float* __restrict__ gxw,
    float* __restrict__ gxout) {
  const int bx = blockIdx.x;
  const int tid = threadIdx.x;
  if (bx < 12800) {
    int c = bx * 256 + tid;
    int k8 = c % (KDIM / 8);
    int row = c / (KDIM / 8);
    int k = k8 * 8;
    const float* src = (k < NI) ? (wih + (size_t)row * NI + k)
                                : (whh + (size_t)row * NH + (k - NI));
    float4 a = *(const float4*)src;
    float4 b = *(const float4*)(src + 4);
    bf16x8 o;
    o[0] = (bf16_t)a.x; o[1] = (bf16_t)a.y; o[2] = (bf16_t)a.z; o[3] = (bf16_t)a.w;
    o[4] = (bf16_t)b.x; o[5] = (bf16_t)b.y; o[6] = (bf16_t)b.z; o[7] = (bf16_t)b.w;
    *(bf16x8*)&Wc[(size_t)c * 8] = o;
  } else if (bx < 19520) {
    int c = (bx - 12800) * 256 + tid;
    int k8 = c % (KDIM / 8);
    int rest = c / (KDIM / 8);  // n*512 + b
    int n = rest / NB;
    int b = rest % NB;
    int k = k8 * 8;
    const float* src = (k < NI) ? (input + ((size_t)b * NN + n) * NI + k)
                                : (hx + ((size_t)b * NN + n) * NH + (k - NI));
    float4 a = *(const float4*)src;
    float4 d = *(const float4*)(src + 4);
    bf16x8 o;
    o[0] = (bf16_t)a.x; o[1] = (bf16_t)a.y; o[2] = (bf16_t)a.z; o[3] = (bf16_t)a.w;
    o[4] = (bf16_t)d.x; o[5] = (bf16_t)d.y; o[6] = (bf16_t)d.z; o[7] = (bf16_t)d.w;
    *(bf16x8*)&Xc[(size_t)c * 8] = o;
  } else {
    int m = tid;
    if (m < NN) {
      float s = 0.f;
      for (int j = 0; j < NN; j++) s += fabsf(G[m * NN + j]);
      s = fmaxf(s, 1e-12f);
      float row[NN];
      float s2 = 0.f;
      for (int j = 0; j < NN; j++) {
        row[j] = G[m * NN + j] / s;
        s2 += fabsf(row[j]);
      }
      s2 = fmaxf(s2, 1e-12f);
      for (int j = 0; j < NN; j++) {
        gxw[m * NN + j] = row[j];
        gxout[m * NN + j] = row[j] / s2;
      }
    }
  }
}

// ---- GEMM: 128x256 block, BK=64, 4 waves, single-buffer 48 KiB LDS ---------
// gates[b][n][o] = Xc[n][b][:] . Wc[tau][o][:] + bias   (per node n)
//
// 2 blocks/CU resident. 4 barriers per K-tile (closing barriers only):
// per-wave lgkmcnt(0) guards own ds_reads; the 4 closing barriers carry all
// cross-wave hazards:
//   P0-close: vmcnt(2) publishes B1(t);  separates P0 reads / P1 writes
//   P1-close: vmcnt(6) publishes A-hi(t) [vmcnt(0) at t=19]; P1 reads / P2 writes
//   P2-close: (no vmcnt)                 separates P2 reads / P3 writes
//   P3-close: vmcnt(6) publishes A-lo/B0(t+1)
// vmcnt ledger (per-thread gld16 issues): P1:6, P2:4, P3:2.
// Steady state: 6 outstanding entering P0; never drained to 0 mid-loop.
// Swizzle (G4-validated, 128-B rows): 16B chunk, phys = lc ^ (row & 7),
// applied to global source at stage time AND the ds_read address.
__global__ __launch_bounds__(256, 2) void gemm_bt(
    const bf16_t* __restrict__ Xc, const bf16_t* __restrict__ Wc,
    const float* __restrict__ bhh, const int* __restrict__ node_types,
    bf16_t* __restrict__ gates) {
  __shared__ char lds[49152];

  // XCD-bijective remap: 1344 = 8*168; XCD k gets logical blocks [168k,168k+168)
  // n0-major within a node: 4 consecutive blocks share one B panel (L2 reuse).
  const int bid = blockIdx.x;
  const int l = (bid & 7) * 168 + (bid >> 3);
  const int n = l / 64;
  const int rem = l & 63;
  const int m0 = (rem & 3) * 128;
  const int n0 = (rem >> 2) * 256;

  const int tau = node_types[n];
  const bf16_t* An = Xc + (size_t)n * NB * KDIM;
  const bf16_t* Bt = Wc + (size_t)tau * ODIM * KDIM;

  const int tid = threadIdx.x;
  const int lane = tid & 63;
  const int w = tid >> 6;      // 0..3
  const int r = lane & 15;
  const int quad = lane >> 4;

  // fragment read offsets: phys16B = (kk*4+quad) ^ (r&7); kk=1 is ^64 bytes
  const int pA = (quad ^ (r & 7)) * 16;
  const int aoff = r * 128 + pA;                      // + i*2048 + q_m*8192
  const int boff = 16384 + w * 4096 + r * 128 + pA;   // + j*2048 + q_n*16384

  // staging pointers (A-hi = A-lo + 64*KDIM, B1 = B0 + 32*KDIM; same lc)
  const bf16_t* sAlo[2];
  const bf16_t* sB0[4];
#pragma unroll
  for (int p = 0; p < 2; p++) {
    int ci = tid + p * 256;
    int row = ci >> 3, lc = (ci & 7) ^ (row & 7);
    sAlo[p] = An + (size_t)(m0 + row) * KDIM + lc * 8;
  }
#pragma unroll
  for (int p = 0; p < 4; p++) {
    int ci = tid + p * 256;
    int lr = ci >> 3, lc = (ci & 7) ^ (lr & 7);
    int R0 = (lr >> 5) * 64 + (lr & 31);
    sB0[p] = Bt + (size_t)(n0 + R0) * KDIM + lc * 8;
  }

  f32x4 acc[8][4];
#pragma unroll
  for (int i = 0; i < 8; i++)
#pragma unroll
    for (int j = 0; j < 4; j++) acc[i][j] = {0.f, 0.f, 0.f, 0.f};

  // prologue: stage tile 0, FIFO order [Alo, B0, B1, Ahi]; keep [B1,Ahi] flying
  {
#pragma unroll
    for (int p = 0; p < 2; p++) gld16(sAlo[p], lds + tid * 16 + p * 4096);
#pragma unroll
    for (int p = 0; p < 4; p++) gld16(sB0[p], lds + 16384 + tid * 16 + p * 4096);
#pragma unroll
    for (int p = 0; p < 4; p++)
      gld16(sB0[p] + 32 * KDIM, lds + 32768 + tid * 16 + p * 4096);
#pragma unroll
    for (int p = 0; p < 2; p++)
      gld16(sAlo[p] + 64 * KDIM, lds + 8192 + tid * 16 + p * 4096);
#pragma unroll
    for (int p = 0; p < 2; p++) sAlo[p] += 64;
#pragma unroll
    for (int p = 0; p < 4; p++) sB0[p] += 64;
    asm volatile("s_waitcnt vmcnt(6)" ::: "memory");
    wg_barrier();
  }

  bf16x8 af[4][2], b0v[2][2], b1v[2][2];

  for (int t = 0; t < 20; ++t) {
    const bool st = (t < 19);
    // ---------------- P0: A-lo + B0 reads, mfma quad (0,0)
#pragma unroll
    for (int i = 0; i < 4; i++) {
      af[i][0] = *(const bf16x8*)(lds + (aoff + i * 2048));
      af[i][1] = *(const bf16x8*)(lds + ((aoff + i * 2048) ^ 64));
    }
#pragma unroll
    for (int j = 0; j < 2; j++) {
      b0v[j][0] = *(const bf16x8*)(lds + (boff + j * 2048));
      b0v[j][1] = *(const bf16x8*)(lds + ((boff + j * 2048) ^ 64));
    }
    asm volatile("s_waitcnt lgkmcnt(0)" ::: "memory");
    __builtin_amdgcn_sched_barrier(0);
    __builtin_amdgcn_s_setprio(1);
#pragma unroll
    for (int i = 0; i < 4; i++)
#pragma unroll
      for (int j = 0; j < 2; j++) {
        acc[i][j] = __builtin_amdgcn_mfma_f32_16x16x32_bf16(af[i][0], b0v[j][0], acc[i][j], 0, 0, 0);
        acc[i][j] = __builtin_amdgcn_mfma_f32_16x16x32_bf16(af[i][1], b0v[j][1], acc[i][j], 0, 0, 0);
      }
    __builtin_amdgcn_s_setprio(0);
    asm volatile("s_waitcnt vmcnt(2)" ::: "memory");  // B1(t) landed
    wg_barrier();

    // ---------------- P1: B1 reads, stage A-lo'+B0', mfma quad (0,1)
#pragma unroll
    for (int j = 0; j < 2; j++) {
      b1v[j][0] = *(const bf16x8*)(lds + (boff + 16384 + j * 2048));
      b1v[j][1] = *(const bf16x8*)(lds + ((boff + 16384 + j * 2048) ^ 64));
    }
    if (st) {
#pragma unroll
      for (int p = 0; p < 2; p++) gld16(sAlo[p], lds + tid * 16 + p * 4096);
#pragma unroll
      for (int p = 0; p < 4; p++) gld16(sB0[p], lds + 16384 + tid * 16 + p * 4096);
    }
    asm volatile("s_waitcnt lgkmcnt(0)" ::: "memory");
    __builtin_amdgcn_sched_barrier(0);
    __builtin_amdgcn_s_setprio(1);
#pragma unroll
    for (int i = 0; i < 4; i++)
#pragma unroll
      for (int j = 0; j < 2; j++) {
        acc[i][2 + j] = __builtin_amdgcn_mfma_f32_16x16x32_bf16(af[i][0], b1v[j][0], acc[i][2 + j], 0, 0, 0);
        acc[i][2 + j] = __builtin_amdgcn_mfma_f32_16x16x32_bf16(af[i][1], b1v[j][1], acc[i][2 + j], 0, 0, 0);
      }
    __builtin_amdgcn_s_setprio(0);
    if (st) asm volatile("s_waitcnt vmcnt(6)" ::: "memory");   // A-hi(t) landed
    else    asm volatile("s_waitcnt vmcnt(0)" ::: "memory");
    wg_barrier();

    // ---------------- P2: A-hi reads, stage B1', mfma quad (1,1)
#pragma unroll
    for (int i = 0; i < 4; i++) {
      af[i][0] = *(const bf16x8*)(lds + (aoff + 8192 + i * 2048));
      af[i][1] = *(const bf16x8*)(lds + ((aoff + 8192 + i * 2048) ^ 64));
    }
    if (st) {
#pragma unroll
      for (int p = 0; p < 4; p++)
        gld16(sB0[p] + 32 * KDIM, lds + 32768 + tid * 16 + p * 4096);
    }
    asm volatile("s_waitcnt lgkmcnt(0)" ::: "memory");
    __builtin_amdgcn_sched_barrier(0);
    __builtin_amdgcn_s_setprio(1);
#pragma unroll
    for (int i = 0; i < 4; i++)
#pragma unroll
      for (int j = 0; j < 2; j++) {
        acc[4 + i][2 + j] = __builtin_amdgcn_mfma_f32_16x16x32_bf16(af[i][0], b1v[j][0], acc[4 + i][2 + j], 0, 0, 0);
        acc[4 + i][2 + j] = __builtin_amdgcn_mfma_f32_16x16x32_bf16(af[i][1], b1v[j][1], acc[4 + i][2 + j], 0, 0, 0);
      }
    __builtin_amdgcn_s_setprio(0);
    wg_barrier();

    // ---------------- P3: stage A-hi', mfma quad (1,0) with held af/b0v
    if (st) {
#pragma unroll
      for (int p = 0; p < 2; p++)
        gld16(sAlo[p] + 64 * KDIM, lds + 8192 + tid * 16 + p * 4096);
    }
    __builtin_amdgcn_s_setprio(1);
#pragma unroll
    for (int i = 0; i < 4; i++)
#pragma unroll
      for (int j = 0; j < 2; j++) {
        acc[4 + i][j] = __builtin_amdgcn_mfma_f32_16x16x32_bf16(af[i][0], b0v[j][0], acc[4 + i][j], 0, 0, 0);
        acc[4 + i][j] = __builtin_amdgcn_mfma_f32_16x16x32_bf16(af[i][1], b0v[j][1], acc[4 + i][j], 0, 0, 0);
      }
    __builtin_amdgcn_s_setprio(0);
    if (st) asm volatile("s_waitcnt vmcnt(6)" ::: "memory");  // A-lo',B0' landed
    wg_barrier();

#pragma unroll
    for (int p = 0; p < 2; p++) sAlo[p] += 64;
#pragma unroll
    for (int p = 0; p < 4; p++) sB0[p] += 64;
  }

  float bv[4];
#pragma unroll
  for (int j = 0; j < 4; j++) bv[j] = bhh[tau * ODIM + n0 + w * 64 + j * 16 + r];
#pragma unroll
  for (int i = 0; i < 8; i++) {
    int brow = m0 + i * 16 + quad * 4;
#pragma unroll
    for (int j = 0; j < 4; j++) {
      int o = n0 + w * 64 + j * 16 + r;
#pragma unroll
      for (int reg = 0; reg < 4; reg++) {
        int b = brow + reg;
        gates[((size_t)b * NN + n) * ODIM + o] = (bf16_t)(acc[i][j][reg] + bv[j]);
      }
    }
  }
}

// ---- fused mix + pointwise LSTM --------------------------------------------
template <int M0C, int CH>
__device__ inline void mix_chunk(const bf16_t (*gs)[4][256],
                                 const float* __restrict__ gx,
                                 const float* __restrict__ cx,
                                 float* __restrict__ out, int b, int h, int tid,
                                 bool cmask) {
  float a[CH][4];
#pragma unroll
  for (int mm = 0; mm < CH; mm++) {
    a[mm][0] = 0.f; a[mm][1] = 0.f; a[mm][2] = 0.f; a[mm][3] = 0.f;
  }
  for (int nn = 0; nn < NN; nn++) {
    float v0 = (float)gs[nn][0][tid];
    float v1 = (float)gs[nn][1][tid];
    float v2 = (float)gs[nn][2][tid];
    float v3 = (float)gs[nn][3][tid];
#pragma unroll
    for (int mm = 0; mm < CH; mm++) {
      float wgt = gx[(M0C + mm) * NN + nn];  // wave-uniform -> SGPR
      a[mm][0] = fmaf(wgt, v0, a[mm][0]);
      a[mm][1] = fmaf(wgt, v1, a[mm][1]);
      a[mm][2] = fmaf(wgt, v2, a[mm][2]);
      a[mm][3] = fmaf(wgt, v3, a[mm][3]);
    }
  }
#pragma unroll
  for (int mm = 0; mm < CH; mm++) {
    int m = M0C + mm;
    size_t off = ((size_t)b * NN + m) * NH + h;
    float c0 = cx[off];
    float ig = sigmoid_fast(a[mm][0]);
    float fg = sigmoid_fast(a[mm][1]);
    float cg = tanh_fast(a[mm][2]);
    float og = sigmoid_fast(a[mm][3]);
    float c = cmask ? fmaf(fg, c0, ig * cg) : c0;
    out[off] = og * tanh_fast(c);
    out[BNH + off] = c;
  }
}

__global__ __launch_bounds__(256) void mix_lstm(const bf16_t* __restrict__ gates,
                                                const float* __restrict__ gx,
                                                const float* __restrict__ cx,
                                                const int* __restrict__ t_ptr,
                                                float* __restrict__ out) {
  __shared__ bf16_t gs[NN][4][256];  // 43,008 B
  const int tid = threadIdx.x;
  const int b = blockIdx.y;
  const int h0 = blockIdx.x * 256;
  const size_t gb = (size_t)b * NN * ODIM;
  for (int i = tid; i < NN * 4 * 32; i += 256) {
    int nn = i >> 7;
    int rem = i & 127;
    int g = rem >> 5;
    int c = rem & 31;
    *(bf16x8*)&gs[nn][g][c * 8] =
        *(const bf16x8*)&gates[gb + (size_t)nn * ODIM + g * NH + h0 + c * 8];
  }
  __syncthreads();

  const int h = h0 + tid;
  const float tf = (float)(t_ptr[0] + 1);
  float phase = floorf((float)h / 1023.0f * 8.0f + 1.0f);  // 1..9
  bool cmask = fmodf(tf, phase) < 0.01f;

  mix_chunk<0, 11>(gs, gx, cx, out, b, h, tid, cmask);
  mix_chunk<11, 10>(gs, gx, cx, out, b, h, tid, cmask);
}

extern "C" void kernel_launch(void* const* d_in, const int* in_sizes, int n_in,
                              void* d_out, int out_size, void* d_ws, size_t ws_size,
                              hipStream_t stream) {
  const float* input = (const float*)d_in[0];
  const float* hx = (const float*)d_in[1];
  const float* cx = (const float*)d_in[2];
  const float* G = (const float*)d_in[3];
  const float* wih = (const float*)d_in[4];
  const float* whh = (const float*)d_in[5];
  const float* bhh = (const float*)d_in[6];
  const int* node_types = (const int*)d_in[7];
  const int* t = (const int*)d_in[8];
  float* out = (float*)d_out;

  char* ws = (char*)d_ws;
  bf16_t* Wc = (bf16_t*)ws;
  bf16_t* Xc = (bf16_t*)(ws + 52428800);
  bf16_t* gates = (bf16_t*)(ws + 79953920);
  float* gxw = (float*)(ws + 168034304);

  pack_all<<<19521, 256, 0, stream>>>(wih, whh, input, hx, G, Wc, Xc, gxw,
                                      out + 2 * BNH);
  gemm_bt<<<1344, 256, 0, stream>>>(Xc, Wc, bhh, node_types, gates);
  dim3 gm(NH / 256, NB);  // (4, 512)
  mix_lstm<<<gm, 256, 0, stream>>>(gates, gxw, cx, t, out);
}

// Round 5
// 400.397 us; speedup vs baseline: 1.0958x; 1.0114x over previous
//
#include <hip/hip_runtime.h>
#include <hip/hip_bf16.h>
#include <stdint.h>

// StaticGraphLSTMCell: B=512, N=21, I=256, H=1024, NT=5
// out = [hy (B*N*H) | cy (B*N*H) | gx_out (N*N)] fp32
//
// ws layout (bytes):
//   Wc   bf16 [5][4096][1280]   @ 0          (52,428,800)
//   Xc   bf16 [21][512][1280]   @ 52,428,800 (27,525,120)
//   gates bf16 [512][21][4096]  @ 79,953,920 (88,080,384)
//   gx   f32  [21][21]          @ 168,034,304 (1,764)

typedef __bf16 bf16_t;
typedef __bf16 bf16x8 __attribute__((ext_vector_type(8)));
typedef float f32x4 __attribute__((ext_vector_type(4)));

#define NB 512
#define NN 21
#define NI 256
#define NH 1024
#define KDIM 1280
#define ODIM 4096
#define BNH (512ull * 21 * 1024)

__device__ inline void gld16(const void* g, const void* l) {
  __builtin_amdgcn_global_load_lds(
      (const __attribute__((address_space(1))) unsigned int*)g,
      (__attribute__((address_space(3))) unsigned int*)l, 16, 0, 0);
}

__device__ inline float sigmoid_fast(float x) {
  return 1.0f / (1.0f + __expf(-x));
}
__device__ inline float tanh_fast(float x) {
  float ax = fabsf(x);
  float e = __expf(2.0f * ax);  // inf-safe: 2/(inf+1)=0 -> 1
  float t = 1.0f - 2.0f / (e + 1.0f);
  return copysignf(t, x);
}

__device__ inline void wg_barrier() {
  asm volatile("" ::: "memory");
  __builtin_amdgcn_s_barrier();
  asm volatile("" ::: "memory");
}

// ---- merged prep: pack weights, pack activations, gx normalize -------------
__global__ __launch_bounds__(256) void pack_all(
    const float* __restrict__ wih, const float* __restrict__ whh,
    const float* __restrict__ input, const float* __restrict__ hx,
    const float* __restrict__ G, bf16_t* __restrict__ Wc,
    bf16_t* __restrict__ Xc, float* __restrict__ gxw,
    float* __restrict__ gxout) {
  const int bx = blockIdx.x;
  const int tid = threadIdx.x;
  if (bx < 12800) {
    int c = bx * 256 + tid;
    int k8 = c % (KDIM / 8);
    int row = c / (KDIM / 8);
    int k = k8 * 8;
    const float* src = (k < NI) ? (wih + (size_t)row * NI + k)
                                : (whh + (size_t)row * NH + (k - NI));
    float4 a = *(const float4*)src;
    float4 b = *(const float4*)(src + 4);
    bf16x8 o;
    o[0] = (bf16_t)a.x; o[1] = (bf16_t)a.y; o[2] = (bf16_t)a.z; o[3] = (bf16_t)a.w;
    o[4] = (bf16_t)b.x; o[5] = (bf16_t)b.y; o[6] = (bf16_t)b.z; o[7] = (bf16_t)b.w;
    *(bf16x8*)&Wc[(size_t)c * 8] = o;
  } else if (bx < 19520) {
    int c = (bx - 12800) * 256 + tid;
    int k8 = c % (KDIM / 8);
    int rest = c / (KDIM / 8);  // n*512 + b
    int n = rest / NB;
    int b = rest % NB;
    int k = k8 * 8;
    const float* src = (k < NI) ? (input + ((size_t)b * NN + n) * NI + k)
                                : (hx + ((size_t)b * NN + n) * NH + (k - NI));
    float4 a = *(const float4*)src;
    float4 d = *(const float4*)(src + 4);
    bf16x8 o;
    o[0] = (bf16_t)a.x; o[1] = (bf16_t)a.y; o[2] = (bf16_t)a.z; o[3] = (bf16_t)a.w;
    o[4] = (bf16_t)d.x; o[5] = (bf16_t)d.y; o[6] = (bf16_t)d.z; o[7] = (bf16_t)d.w;
    *(bf16x8*)&Xc[(size_t)c * 8] = o;
  } else {
    int m = tid;
    if (m < NN) {
      float s = 0.f;
      for (int j = 0; j < NN; j++) s += fabsf(G[m * NN + j]);
      s = fmaxf(s, 1e-12f);
      float row[NN];
      float s2 = 0.f;
      for (int j = 0; j < NN; j++) {
        row[j] = G[m * NN + j] / s;
        s2 += fabsf(row[j]);
      }
      s2 = fmaxf(s2, 1e-12f);
      for (int j = 0; j < NN; j++) {
        gxw[m * NN + j] = row[j];
        gxout[m * NN + j] = row[j] / s2;
      }
    }
  }
}

// ---- GEMM: 128x256 block, BK=64, 4 waves, single-buffer 48 KiB LDS ---------
// gates[b][n][o] = Xc[n][b][:] . Wc[tau][o][:] + bias   (per node n)
//
// 2 blocks/CU resident. 4 barriers per K-tile (closing barriers only).
// NO manual lgkmcnt drains: ds_reads are plain C++ loads, so the compiler
// tracks read->MFMA deps and emits counted lgkmcnt(N), interleaving LDS
// reads with MFMAs (the R4 manual lgkmcnt(0)+sched_barrier serialized the
// two pipes: wall/instance 2546cy ~= MFMA 1242 + LDS 1156 back-to-back).
// Staging gld16s are issued at phase top (HBM starts earliest; destination
// regions are disjoint from that phase's read regions).
// Cross-wave hazards, all carried by the 4 closing barriers:
//   P0-close: vmcnt(2) publishes B1(t);  separates P0 reads / P1 writes
//   P1-close: vmcnt(6) publishes A-hi(t) [vmcnt(0) at t=19]; P1 reads / P2 writes
//   P2-close: (no vmcnt)                 separates P2 reads / P3 writes
//   P3-close: vmcnt(6) publishes A-lo/B0(t+1)
// vmcnt ledger (per-thread gld16 issues): P1:+6, P2:+4, P3:+2; steady state
// enters P0 with 6 outstanding; never drained to 0 mid-loop.
// Swizzle (G4-validated, 128-B rows): 16B chunk, phys = lc ^ (row & 7),
// applied to global source at stage time AND the ds_read address.
__global__ __launch_bounds__(256, 2) void gemm_bt(
    const bf16_t* __restrict__ Xc, const bf16_t* __restrict__ Wc,
    const float* __restrict__ bhh, const int* __restrict__ node_types,
    bf16_t* __restrict__ gates) {
  __shared__ char lds[49152];

  // XCD-bijective remap: 1344 = 8*168; XCD k gets logical blocks [168k,168k+168)
  // n0-major within a node: 4 consecutive blocks share one B panel (L2 reuse).
  const int bid = blockIdx.x;
  const int l = (bid & 7) * 168 + (bid >> 3);
  const int n = l / 64;
  const int rem = l & 63;
  const int m0 = (rem & 3) * 128;
  const int n0 = (rem >> 2) * 256;

  const int tau = node_types[n];
  const bf16_t* An = Xc + (size_t)n * NB * KDIM;
  const bf16_t* Bt = Wc + (size_t)tau * ODIM * KDIM;

  const int tid = threadIdx.x;
  const int lane = tid & 63;
  const int w = tid >> 6;      // 0..3
  const int r = lane & 15;
  const int quad = lane >> 4;

  // fragment read offsets: phys16B = (kk*4+quad) ^ (r&7); kk=1 is ^64 bytes
  const int pA = (quad ^ (r & 7)) * 16;
  const int aoff = r * 128 + pA;                      // + i*2048 + q_m*8192
  const int boff = 16384 + w * 4096 + r * 128 + pA;   // + j*2048 + q_n*16384

  // staging pointers (A-hi = A-lo + 64*KDIM, B1 = B0 + 32*KDIM; same lc)
  const bf16_t* sAlo[2];
  const bf16_t* sB0[4];
#pragma unroll
  for (int p = 0; p < 2; p++) {
    int ci = tid + p * 256;
    int row = ci >> 3, lc = (ci & 7) ^ (row & 7);
    sAlo[p] = An + (size_t)(m0 + row) * KDIM + lc * 8;
  }
#pragma unroll
  for (int p = 0; p < 4; p++) {
    int ci = tid + p * 256;
    int lr = ci >> 3, lc = (ci & 7) ^ (lr & 7);
    int R0 = (lr >> 5) * 64 + (lr & 31);
    sB0[p] = Bt + (size_t)(n0 + R0) * KDIM + lc * 8;
  }

  f32x4 acc[8][4];
#pragma unroll
  for (int i = 0; i < 8; i++)
#pragma unroll
    for (int j = 0; j < 4; j++) acc[i][j] = {0.f, 0.f, 0.f, 0.f};

  // prologue: stage tile 0, FIFO order [Alo, B0, B1, Ahi]; keep [B1,Ahi] flying
  {
#pragma unroll
    for (int p = 0; p < 2; p++) gld16(sAlo[p], lds + tid * 16 + p * 4096);
#pragma unroll
    for (int p = 0; p < 4; p++) gld16(sB0[p], lds + 16384 + tid * 16 + p * 4096);
#pragma unroll
    for (int p = 0; p < 4; p++)
      gld16(sB0[p] + 32 * KDIM, lds + 32768 + tid * 16 + p * 4096);
#pragma unroll
    for (int p = 0; p < 2; p++)
      gld16(sAlo[p] + 64 * KDIM, lds + 8192 + tid * 16 + p * 4096);
#pragma unroll
    for (int p = 0; p < 2; p++) sAlo[p] += 64;
#pragma unroll
    for (int p = 0; p < 4; p++) sB0[p] += 64;
    asm volatile("s_waitcnt vmcnt(6)" ::: "memory");
    wg_barrier();
  }

  bf16x8 af[4][2], b0v[2][2], b1v[2][2];

  for (int t = 0; t < 20; ++t) {
    const bool st = (t < 19);
    // ---------------- P0: A-lo + B0 reads, mfma quad (0,0)
#pragma unroll
    for (int i = 0; i < 4; i++) {
      af[i][0] = *(const bf16x8*)(lds + (aoff + i * 2048));
      af[i][1] = *(const bf16x8*)(lds + ((aoff + i * 2048) ^ 64));
    }
#pragma unroll
    for (int j = 0; j < 2; j++) {
      b0v[j][0] = *(const bf16x8*)(lds + (boff + j * 2048));
      b0v[j][1] = *(const bf16x8*)(lds + ((boff + j * 2048) ^ 64));
    }
    __builtin_amdgcn_s_setprio(1);
#pragma unroll
    for (int i = 0; i < 4; i++)
#pragma unroll
      for (int j = 0; j < 2; j++) {
        acc[i][j] = __builtin_amdgcn_mfma_f32_16x16x32_bf16(af[i][0], b0v[j][0], acc[i][j], 0, 0, 0);
        acc[i][j] = __builtin_amdgcn_mfma_f32_16x16x32_bf16(af[i][1], b0v[j][1], acc[i][j], 0, 0, 0);
      }
    __builtin_amdgcn_s_setprio(0);
    asm volatile("s_waitcnt vmcnt(2)" ::: "memory");  // B1(t) landed
    wg_barrier();

    // ---------------- P1: stage A-lo'+B0', B1 reads, mfma quad (0,1)
    if (st) {
#pragma unroll
      for (int p = 0; p < 2; p++) gld16(sAlo[p], lds + tid * 16 + p * 4096);
#pragma unroll
      for (int p = 0; p < 4; p++) gld16(sB0[p], lds + 16384 + tid * 16 + p * 4096);
    }
#pragma unroll
    for (int j = 0; j < 2; j++) {
      b1v[j][0] = *(const bf16x8*)(lds + (boff + 16384 + j * 2048));
      b1v[j][1] = *(const bf16x8*)(lds + ((boff + 16384 + j * 2048) ^ 64));
    }
    __builtin_amdgcn_s_setprio(1);
#pragma unroll
    for (int i = 0; i < 4; i++)
#pragma unroll
      for (int j = 0; j < 2; j++) {
        acc[i][2 + j] = __builtin_amdgcn_mfma_f32_16x16x32_bf16(af[i][0], b1v[j][0], acc[i][2 + j], 0, 0, 0);
        acc[i][2 + j] = __builtin_amdgcn_mfma_f32_16x16x32_bf16(af[i][1], b1v[j][1], acc[i][2 + j], 0, 0, 0);
      }
    __builtin_amdgcn_s_setprio(0);
    if (st) asm volatile("s_waitcnt vmcnt(6)" ::: "memory");   // A-hi(t) landed
    else    asm volatile("s_waitcnt vmcnt(0)" ::: "memory");
    wg_barrier();

    // ---------------- P2: stage B1', A-hi reads, mfma quad (1,1)
    if (st) {
#pragma unroll
      for (int p = 0; p < 4; p++)
        gld16(sB0[p] + 32 * KDIM, lds + 32768 + tid * 16 + p * 4096);
    }
#pragma unroll
    for (int i = 0; i < 4; i++) {
      af[i][0] = *(const bf16x8*)(lds + (aoff + 8192 + i * 2048));
      af[i][1] = *(const bf16x8*)(lds + ((aoff + 8192 + i * 2048) ^ 64));
    }
    __builtin_amdgcn_s_setprio(1);
#pragma unroll
    for (int i = 0; i < 4; i++)
#pragma unroll
      for (int j = 0; j < 2; j++) {
        acc[4 + i][2 + j] = __builtin_amdgcn_mfma_f32_16x16x32_bf16(af[i][0], b1v[j][0], acc[4 + i][2 + j], 0, 0, 0);
        acc[4 + i][2 + j] = __builtin_amdgcn_mfma_f32_16x16x32_bf16(af[i][1], b1v[j][1], acc[4 + i][2 + j], 0, 0, 0);
      }
    __builtin_amdgcn_s_setprio(0);
    wg_barrier();

    // ---------------- P3: stage A-hi', mfma quad (1,0) with held af/b0v
    if (st) {
#pragma unroll
      for (int p = 0; p < 2; p++)
        gld16(sAlo[p] + 64 * KDIM, lds + 8192 + tid * 16 + p * 4096);
    }
    __builtin_amdgcn_s_setprio(1);
#pragma unroll
    for (int i = 0; i < 4; i++)
#pragma unroll
      for (int j = 0; j < 2; j++) {
        acc[4 + i][j] = __builtin_amdgcn_mfma_f32_16x16x32_bf16(af[i][0], b0v[j][0], acc[4 + i][j], 0, 0, 0);
        acc[4 + i][j] = __builtin_amdgcn_mfma_f32_16x16x32_bf16(af[i][1], b0v[j][1], acc[4 + i][j], 0, 0, 0);
      }
    __builtin_amdgcn_s_setprio(0);
    if (st) asm volatile("s_waitcnt vmcnt(6)" ::: "memory");  // A-lo',B0' landed
    wg_barrier();

#pragma unroll
    for (int p = 0; p < 2; p++) sAlo[p] += 64;
#pragma unroll
    for (int p = 0; p < 4; p++) sB0[p] += 64;
  }

  float bv[4];
#pragma unroll
  for (int j = 0; j < 4; j++) bv[j] = bhh[tau * ODIM + n0 + w * 64 + j * 16 + r];
#pragma unroll
  for (int i = 0; i < 8; i++) {
    int brow = m0 + i * 16 + quad * 4;
#pragma unroll
    for (int j = 0; j < 4; j++) {
      int o = n0 + w * 64 + j * 16 + r;
#pragma unroll
      for (int reg = 0; reg < 4; reg++) {
        int b = brow + reg;
        gates[((size_t)b * NN + n) * ODIM + o] = (bf16_t)(acc[i][j][reg] + bv[j]);
      }
    }
  }
}

// ---- fused mix + pointwise LSTM --------------------------------------------
template <int M0C, int CH>
__device__ inline void mix_chunk(const bf16_t (*gs)[4][256],
                                 const float* __restrict__ gx,
                                 const float* __restrict__ cx,
                                 float* __restrict__ out, int b, int h, int tid,
                                 bool cmask) {
  float a[CH][4];
#pragma unroll
  for (int mm = 0; mm < CH; mm++) {
    a[mm][0] = 0.f; a[mm][1] = 0.f; a[mm][2] = 0.f; a[mm][3] = 0.f;
  }
  for (int nn = 0; nn < NN; nn++) {
    float v0 = (float)gs[nn][0][tid];
    float v1 = (float)gs[nn][1][tid];
    float v2 = (float)gs[nn][2][tid];
    float v3 = (float)gs[nn][3][tid];
#pragma unroll
    for (int mm = 0; mm < CH; mm++) {
      float wgt = gx[(M0C + mm) * NN + nn];  // wave-uniform -> SGPR
      a[mm][0] = fmaf(wgt, v0, a[mm][0]);
      a[mm][1] = fmaf(wgt, v1, a[mm][1]);
      a[mm][2] = fmaf(wgt, v2, a[mm][2]);
      a[mm][3] = fmaf(wgt, v3, a[mm][3]);
    }
  }
#pragma unroll
  for (int mm = 0; mm < CH; mm++) {
    int m = M0C + mm;
    size_t off = ((size_t)b * NN + m) * NH + h;
    float c0 = cx[off];
    float ig = sigmoid_fast(a[mm][0]);
    float fg = sigmoid_fast(a[mm][1]);
    float cg = tanh_fast(a[mm][2]);
    float og = sigmoid_fast(a[mm][3]);
    float c = cmask ? fmaf(fg, c0, ig * cg) : c0;
    out[off] = og * tanh_fast(c);
    out[BNH + off] = c;
  }
}

__global__ __launch_bounds__(256) void mix_lstm(const bf16_t* __restrict__ gates,
                                                const float* __restrict__ gx,
                                                const float* __restrict__ cx,
                                                const int* __restrict__ t_ptr,
                                                float* __restrict__ out) {
  __shared__ bf16_t gs[NN][4][256];  // 43,008 B
  const int tid = threadIdx.x;
  const int b = blockIdx.y;
  const int h0 = blockIdx.x * 256;
  const size_t gb = (size_t)b * NN * ODIM;
  for (int i = tid; i < NN * 4 * 32; i += 256) {
    int nn = i >> 7;
    int rem = i & 127;
    int g = rem >> 5;
    int c = rem & 31;
    *(bf16x8*)&gs[nn][g][c * 8] =
        *(const bf16x8*)&gates[gb + (size_t)nn * ODIM + g * NH + h0 + c * 8];
  }
  __syncthreads();

  const int h = h0 + tid;
  const float tf = (float)(t_ptr[0] + 1);
  float phase = floorf((float)h / 1023.0f * 8.0f + 1.0f);  // 1..9
  bool cmask = fmodf(tf, phase) < 0.01f;

  mix_chunk<0, 11>(gs, gx, cx, out, b, h, tid, cmask);
  mix_chunk<11, 10>(gs, gx, cx, out, b, h, tid, cmask);
}

extern "C" void kernel_launch(void* const* d_in, const int* in_sizes, int n_in,
                              void* d_out, int out_size, void* d_ws, size_t ws_size,
                              hipStream_t stream) {
  const float* input = (const float*)d_in[0];
  const float* hx = (const float*)d_in[1];
  const float* cx = (const float*)d_in[2];
  const float* G = (const float*)d_in[3];
  const float* wih = (const float*)d_in[4];
  const float* whh = (const float*)d_in[5];
  const float* bhh = (const float*)d_in[6];
  const int* node_types = (const int*)d_in[7];
  const int* t = (const int*)d_in[8];
  float* out = (float*)d_out;

  char* ws = (char*)d_ws;
  bf16_t* Wc = (bf16_t*)ws;
  bf16_t* Xc = (bf16_t*)(ws + 52428800);
  bf16_t* gates = (bf16_t*)(ws + 79953920);
  float* gxw = (float*)(ws + 168034304);

  pack_all<<<19521, 256, 0, stream>>>(wih, whh, input, hx, G, Wc, Xc, gxw,
                                      out + 2 * BNH);
  gemm_bt<<<1344, 256, 0, stream>>>(Xc, Wc, bhh, node_types, gates);
  dim3 gm(NH / 256, NB);  // (4, 512)
  mix_lstm<<<gm, 256, 0, stream>>>(gates, gxw, cx, t, out);
}